// Round 1
// 352.178 us; speedup vs baseline: 1.0323x; 1.0323x over previous
//
#include <hip/hip_runtime.h>

// SelfAttention truncated forward: scores = (Xq Wq + bq)(Xk Wk + bk)^T / 8
// Inputs FP32, output FP32. Internal Q/K in bf16 (MFMA), fp32 accumulate.
//
// R1 changes vs 363-µs baseline:
//  - proj: 128-row blocks (256 total = 1 block/CU = 1 wave/SIMD, latency-bound
//    at ~0.4 TB/s) -> 32-row blocks (1024 total = 4 blocks/CU, 16 waves/CU).
//  - score: epilogue was 64 scalar dword stores/thread (64-B segments,
//    partial-line writes). Now: waves own 32x128 tiles; accs are staged
//    through per-wave private LDS (reusing the dead qs/ks staging buffer)
//    and written as 16 global_store_dwordx4/thread with full 128-B-aligned
//    row segments.
constexpr int Bn = 4;      // batch
constexpr int S  = 4096;   // sequence
constexpr int E  = 512;    // embed dim
constexpr int DK = 64;     // d_k
constexpr int XS_STRIDE = DK + 8;   // 64->72 bf16 row stride: uniform bank use

typedef __attribute__((ext_vector_type(8))) short   bf16x8;  // MFMA A/B frag
typedef __attribute__((ext_vector_type(4))) float   f32x4;   // MFMA C/D frag

__device__ __forceinline__ unsigned short f2bf(float f) {
    unsigned x = __builtin_bit_cast(unsigned, f);
    unsigned r = x + 0x7FFFu + ((x >> 16) & 1u);   // RNE
    return (unsigned short)(r >> 16);
}

__device__ __forceinline__ bf16x8 load8_f2bf(const float* __restrict__ p) {
    f32x4 a = *(const f32x4*)p;
    f32x4 b = *(const f32x4*)(p + 4);
    bf16x8 o;
    o[0] = (short)f2bf(a[0]); o[1] = (short)f2bf(a[1]);
    o[2] = (short)f2bf(a[2]); o[3] = (short)f2bf(a[3]);
    o[4] = (short)f2bf(b[0]); o[5] = (short)f2bf(b[1]);
    o[6] = (short)f2bf(b[2]); o[7] = (short)f2bf(b[3]);
    return o;
}

// ---------------------------------------------------------------------------
// Kernel 0: transpose+convert W[512][64] (fp32) -> Wt[64][512] (bf16), Wq & Wk.
// ---------------------------------------------------------------------------
__global__ __launch_bounds__(256) void wt_kernel(const float* __restrict__ Wq,
                                                 const float* __restrict__ Wk,
                                                 unsigned short* __restrict__ Wt) {
    int idx = blockIdx.x * 256 + threadIdx.x;      // 0..32767
    const float* W = blockIdx.y ? Wk : Wq;
    int n = idx >> 9;        // output row (0..63)
    int k = idx & 511;       // output col (0..511)
    Wt[blockIdx.y * (DK * E) + idx] = f2bf(W[k * DK + n]);
}

// ---------------------------------------------------------------------------
// Kernel 1: projection  P[16384][64] = X[16384][512] @ W[512][64] + b
// 32 rows/block -> 1024 blocks -> 4 blocks/CU (was 1): latency hiding via TLP.
// Each of 4 waves owns a 16x32 output sub-tile (wrt = row half, wct = col half).
// blockIdx.y: 0 -> (query, Wq, bq, Qp), 1 -> (key, Wk, bk, Kp)
// ---------------------------------------------------------------------------
__global__ __launch_bounds__(256) void proj_kernel(const float* __restrict__ Xq,
                                                   const float* __restrict__ Xk,
                                                   const unsigned short* __restrict__ Wt,
                                                   const float* __restrict__ bq,
                                                   const float* __restrict__ bk,
                                                   unsigned short* __restrict__ Qp,
                                                   unsigned short* __restrict__ Kp) {
    const float*          X    = blockIdx.y ? Xk : Xq;
    const unsigned short* Wtm  = Wt + (size_t)blockIdx.y * DK * E;
    const float*          bias = blockIdx.y ? bk : bq;
    unsigned short*       P    = blockIdx.y ? Kp : Qp;

    __shared__ unsigned short xs[32][XS_STRIDE];

    const int tid  = threadIdx.x;
    const int wave = tid >> 6;
    const int lane = tid & 63;
    const int quad = lane >> 4;
    const int l16  = lane & 15;
    const long row0 = (long)blockIdx.x * 32;

    const int wrt = (wave & 1) * 16;    // wave's row-tile offset
    const int wct = (wave >> 1) * 32;   // wave's col-tile offset

    // staging assignment: exactly one 8-float chunk per thread per k-step
    const int sr = tid >> 3;            // 0..31
    const int sk = (tid & 7) * 8;       // 0..56
    const float* xsrc = &X[(row0 + sr) * E + sk];

    f32x4 acc[2];
    acc[0] = (f32x4){0.f, 0.f, 0.f, 0.f};
    acc[1] = (f32x4){0.f, 0.f, 0.f, 0.f};

    for (int k0 = 0; k0 < E; k0 += 64) {
        __syncthreads();   // protect xs reuse across iterations
        *(bf16x8*)&xs[sr][sk] = load8_f2bf(xsrc + k0);
        __syncthreads();

        // B fragments straight from global Wt (128 KiB bf16 total, L2 resident)
        bf16x8 bfrag[2][2];
#pragma unroll
        for (int kc = 0; kc < 2; ++kc)
#pragma unroll
            for (int ct = 0; ct < 2; ++ct)
                bfrag[kc][ct] = *(const bf16x8*)&Wtm[(size_t)(wct + ct * 16 + l16) * E + k0 + kc * 32 + quad * 8];

#pragma unroll
        for (int kc = 0; kc < 2; ++kc) {
            bf16x8 af = *(const bf16x8*)&xs[wrt + l16][kc * 32 + quad * 8];
            acc[0] = __builtin_amdgcn_mfma_f32_16x16x32_bf16(af, bfrag[kc][0], acc[0], 0, 0, 0);
            acc[1] = __builtin_amdgcn_mfma_f32_16x16x32_bf16(af, bfrag[kc][1], acc[1], 0, 0, 0);
        }
    }

    // epilogue: + bias, convert, store (C/D layout: col=lane&15, row=quad*4+r)
#pragma unroll
    for (int ct = 0; ct < 2; ++ct) {
        float bv = bias[wct + ct * 16 + l16];
#pragma unroll
        for (int r = 0; r < 4; ++r) {
            long row = row0 + wrt + quad * 4 + r;
            P[row * DK + wct + ct * 16 + l16] = f2bf(acc[ct][r] + bv);
        }
    }
}

// ---------------------------------------------------------------------------
// Kernel 2: scores[b][q][k] = Q[b][q][:] . K[b][k][:] * 0.125   (FP32 out)
// 128x128 tile per block; each wave owns a 32x128 slab (wr = wave*32).
// Epilogue transposes acc through per-wave private LDS (aliasing the staging
// buffer after a barrier) to emit float4 stores with full-line segments.
// ---------------------------------------------------------------------------
__global__ __launch_bounds__(256) void score_kernel(const unsigned short* __restrict__ Q,
                                                    const unsigned short* __restrict__ K,
                                                    float* __restrict__ out) {
    // 36864 B: [qs 128x72 bf16][ks 128x72 bf16]; later overlaid by 4 per-wave
    // float wbuf[16][132] (8448 B each, 33792 B total).
    __shared__ __align__(16) char smraw[2 * 128 * XS_STRIDE * 2];
    unsigned short (*qs)[XS_STRIDE] = (unsigned short(*)[XS_STRIDE])smraw;
    unsigned short (*ks)[XS_STRIDE] = (unsigned short(*)[XS_STRIDE])(smraw + 128 * XS_STRIDE * 2);

    const int tid  = threadIdx.x;
    const int wave = tid >> 6;
    const int lane = tid & 63;
    const int quad = lane >> 4;
    const int l16  = lane & 15;

    const int  b     = blockIdx.z;
    const long qrow0 = (long)blockIdx.y * 128;
    const long krow0 = (long)blockIdx.x * 128;
    const unsigned short* Qb = Q + (size_t)b * S * DK;
    const unsigned short* Kb = K + (size_t)b * S * DK;

#pragma unroll
    for (int c = tid; c < 1024; c += 256) {
        int r  = c >> 3;
        int kc = (c & 7) * 8;
        *(bf16x8*)&qs[r][kc] = *(const bf16x8*)&Qb[(qrow0 + r) * DK + kc];
        *(bf16x8*)&ks[r][kc] = *(const bf16x8*)&Kb[(krow0 + r) * DK + kc];
    }
    __syncthreads();

    const int wr = wave * 32;   // wave's 32-row slab, all 128 cols

    bf16x8 afrag[2][2];
#pragma unroll
    for (int rt = 0; rt < 2; ++rt)
#pragma unroll
        for (int kc = 0; kc < 2; ++kc)
            afrag[rt][kc] = *(const bf16x8*)&qs[wr + rt * 16 + l16][kc * 32 + quad * 8];

    f32x4 acc[2][8];
#pragma unroll
    for (int rt = 0; rt < 2; ++rt)
#pragma unroll
        for (int ct = 0; ct < 8; ++ct) acc[rt][ct] = (f32x4){0.f, 0.f, 0.f, 0.f};

    // ct-outer: only one ct's b-frags (8 VGPRs) live at a time
#pragma unroll
    for (int ct = 0; ct < 8; ++ct) {
        bf16x8 b0 = *(const bf16x8*)&ks[ct * 16 + l16][quad * 8];
        bf16x8 b1 = *(const bf16x8*)&ks[ct * 16 + l16][32 + quad * 8];
#pragma unroll
        for (int rt = 0; rt < 2; ++rt) {
            acc[rt][ct] = __builtin_amdgcn_mfma_f32_16x16x32_bf16(afrag[rt][0], b0, acc[rt][ct], 0, 0, 0);
            acc[rt][ct] = __builtin_amdgcn_mfma_f32_16x16x32_bf16(afrag[rt][1], b1, acc[rt][ct], 0, 0, 0);
        }
    }

    __syncthreads();   // all waves done reading qs/ks before the wbuf overlay

    // per-wave private 16x132 f32 transpose buffer (no cross-wave sync needed)
    float (*wbuf)[132] = (float(*)[132])(smraw + (size_t)wave * (16 * 132 * 4));

    float* ob = out + (size_t)b * S * S;
    const int rrow = lane >> 3;         // 0..7
    const int rcol = (lane & 7) * 4;    // 0,4,..,28

#pragma unroll
    for (int rt = 0; rt < 2; ++rt) {
        // scatter acc into row-major wbuf (C/D layout: col=l16, row=quad*4+r)
#pragma unroll
        for (int ct = 0; ct < 8; ++ct)
#pragma unroll
            for (int r = 0; r < 4; ++r)
                wbuf[quad * 4 + r][ct * 16 + l16] = acc[rt][ct][r] * 0.125f;

        // read back row-major: 8 lanes x 16 B = one full 128-B line per row
#pragma unroll
        for (int jr = 0; jr < 2; ++jr)
#pragma unroll
            for (int jc = 0; jc < 4; ++jc) {
                int rr = jr * 8 + rrow;
                int cc = jc * 32 + rcol;
                f32x4 v = *(const f32x4*)&wbuf[rr][cc];
                *(f32x4*)&ob[(qrow0 + wr + rt * 16 + rr) * S + krow0 + cc] = v;
            }
    }
}

// ---------------------------------------------------------------------------
extern "C" void kernel_launch(void* const* d_in, const int* in_sizes, int n_in,
                              void* d_out, int out_size, void* d_ws, size_t ws_size,
                              hipStream_t stream) {
    (void)in_sizes; (void)n_in; (void)out_size; (void)ws_size;

    const float* query = (const float*)d_in[0];
    const float* key   = (const float*)d_in[1];
    const float* Wq    = (const float*)d_in[3];
    const float* bq    = (const float*)d_in[4];
    const float* Wk    = (const float*)d_in[5];
    const float* bk    = (const float*)d_in[6];
    // value_in / Wv / bv (d_in[2], d_in[7], d_in[8]) are dead code in the reference.

    unsigned short* ws = (unsigned short*)d_ws;
    unsigned short* Wt = ws;                       // [2][64][512] bf16   (128 KiB)
    unsigned short* Qp = ws + 2 * DK * E;          // [4][4096][64] bf16  (2 MiB)
    unsigned short* Kp = Qp + (size_t)Bn * S * DK; // [4][4096][64] bf16  (2 MiB)

    float* scores = (float*)d_out;

    wt_kernel<<<dim3(128, 2), 256, 0, stream>>>(Wq, Wk, Wt);
    proj_kernel<<<dim3(Bn * S / 32, 2), 256, 0, stream>>>(query, key, Wt, bq, bk, Qp, Kp);
    score_kernel<<<dim3(S / 128, S / 128, Bn), 256, 0, stream>>>(Qp, Kp, scores);
}